// Round 1
// baseline (643.740 us; speedup 1.0000x reference)
//
#include <hip/hip_runtime.h>
#include <hip/hip_bf16.h>

#define S 16
#define C 8
#define SC 128
#define TT 500
#define NN 1500

__device__ __forceinline__ float fexp2(float x) { return exp2f(x); }
__device__ __forceinline__ float flog2(float x) { return log2f(x); }

#define L2E 1.4426950408889634f
#define LN2 0.6931471805599453f

// ---------------- Kernel A: emission log-softmax over N per state ----------
__global__ __launch_bounds__(256) void emission_kernel(
    const float* __restrict__ uem, float* __restrict__ lem)
{
    const int s0 = blockIdx.x;
    const float* row = uem + s0 * NN;
    const int tid = threadIdx.x;
    __shared__ float sm[4];
    __shared__ float ss[4];

    float m = -1e30f;
    for (int n = tid; n < NN; n += 256) m = fmaxf(m, row[n]);
#pragma unroll
    for (int off = 32; off >= 1; off >>= 1) m = fmaxf(m, __shfl_xor(m, off));
    if ((tid & 63) == 0) sm[tid >> 6] = m;
    __syncthreads();
    const float M = fmaxf(fmaxf(sm[0], sm[1]), fmaxf(sm[2], sm[3]));

    float acc = 0.f;
    for (int n = tid; n < NN; n += 256) acc += fexp2((row[n] - M) * L2E);
#pragma unroll
    for (int off = 32; off >= 1; off >>= 1) acc += __shfl_xor(acc, off);
    if ((tid & 63) == 0) ss[tid >> 6] = acc;
    __syncthreads();
    const float lse = M + flog2(ss[0] + ss[1] + ss[2] + ss[3]) * LN2;

    for (int n = tid; n < NN; n += 256) lem[s0 * NN + n] = row[n] - lse;
}

// ---------------- Kernel B: normalizations + serial HMM scan ---------------
// 1 block, 64 threads (one wave). lane = c*8 + j ; handles s' = j and j+8.
__global__ __launch_bounds__(64) void hmm_serial(
    const float* __restrict__ usi,   // (16,8)
    const float* __restrict__ ucw,   // (500,8)
    const float* __restrict__ utm,   // (8,16,16)
    float* __restrict__ out3,        // (500,16,8) natural log
    float* __restrict__ ws_lcw,      // (500,8)
    float* __restrict__ ws_W)        // (500,16)
{
    __shared__ float lT[SC * S];     // log2-domain normalized transition, row (c,s), col s'
    __shared__ float lcw[TT * C];    // natural log chain weights
    __shared__ float h[SC];          // current h (natural log), layout [s][c]
    const int lane = threadIdx.x;

    // log_softmax chain weights over C per row t
    for (int t = lane; t < TT; t += 64) {
        float x[C]; float m = -1e30f;
#pragma unroll
        for (int cc = 0; cc < C; ++cc) { x[cc] = ucw[t * C + cc]; m = fmaxf(m, x[cc]); }
        float acc = 0.f;
#pragma unroll
        for (int cc = 0; cc < C; ++cc) acc += fexp2((x[cc] - m) * L2E);
        const float lse = m + flog2(acc) * LN2;
#pragma unroll
        for (int cc = 0; cc < C; ++cc) {
            const float v = x[cc] - lse;
            lcw[t * C + cc] = v;
            ws_lcw[t * C + cc] = v;
        }
    }

    // log_softmax transition rows (over s'), stored in log2 domain
    for (int r = lane; r < SC; r += 64) {
        float x[S]; float m = -1e30f;
#pragma unroll
        for (int k = 0; k < S; ++k) { x[k] = utm[r * S + k]; m = fmaxf(m, x[k]); }
        float acc = 0.f;
#pragma unroll
        for (int k = 0; k < S; ++k) acc += fexp2((x[k] - m) * L2E);
        const float lse = m + flog2(acc) * LN2;
#pragma unroll
        for (int k = 0; k < S; ++k) lT[r * S + k] = (x[k] - lse) * L2E;
    }

    // h0 = log_softmax over states per chain
    if (lane < C) {
        const int cc = lane;
        float x[S]; float m = -1e30f;
#pragma unroll
        for (int s0 = 0; s0 < S; ++s0) { x[s0] = usi[s0 * C + cc]; m = fmaxf(m, x[s0]); }
        float acc = 0.f;
#pragma unroll
        for (int s0 = 0; s0 < S; ++s0) acc += fexp2((x[s0] - m) * L2E);
        const float lse = m + flog2(acc) * LN2;
#pragma unroll
        for (int s0 = 0; s0 < S; ++s0) {
            const float v = x[s0] - lse;
            h[s0 * C + cc] = v;
            out3[s0 * C + cc] = v;
        }
    }
    __syncthreads();

    // per-lane transition columns (log2 domain): Ta[s]=logT2[c][s][j], Tb=..[j+8]
    const int c = lane >> 3;
    const int j = lane & 7;
    float Ta[S], Tb[S];
#pragma unroll
    for (int s0 = 0; s0 < S; ++s0) {
        Ta[s0] = lT[(c * S + s0) * S + j];
        Tb[s0] = lT[(c * S + s0) * S + j + 8];
    }

    for (int t = 0; t < TT; ++t) {
        // W[t][s] = LSE_c(h[s,c] + lcw[t,c])  (lanes 0..15)
        if (lane < S) {
            const int s0 = lane;
            float vv[C]; float m = -1e30f;
#pragma unroll
            for (int cc = 0; cc < C; ++cc) {
                vv[cc] = h[s0 * C + cc] + lcw[t * C + cc];
                m = fmaxf(m, vv[cc]);
            }
            float acc = 0.f;
#pragma unroll
            for (int cc = 0; cc < C; ++cc) acc += fexp2((vv[cc] - m) * L2E);
            ws_W[t * S + s0] = m + flog2(acc) * LN2;
        }
        if (t == TT - 1) break;

        // h'[s'] = ln sum_s exp(h[s] + logT[c,s,s'])  — no max-sub needed:
        // h is a normalized log-prob, bounded in ~[-15,0]; exp2 args > -40.
        float sa = 0.f, sb = 0.f;
#pragma unroll
        for (int s0 = 0; s0 < S; ++s0) {
            const float g = h[s0 * C + c] * L2E;
            sa += fexp2(g + Ta[s0]);
            sb += fexp2(g + Tb[s0]);
        }
        const float na = flog2(sa) * LN2;
        const float nb = flog2(sb) * LN2;
        __syncthreads();   // all reads of old h done
        h[j * C + c] = na;
        h[(j + 8) * C + c] = nb;
        float* o = out3 + (size_t)(t + 1) * SC;
        o[j * C + c] = na;
        o[(j + 8) * C + c] = nb;
        __syncthreads();   // writes visible before next reads
    }
}

// ---------------- Kernel C: broadcast-add (out2) + LSE over s (out1) -------
// grid (6, 500), 256 threads; block = (n-tile, t)
__global__ __launch_bounds__(256) void broadcast_kernel(
    const float* __restrict__ lem,   // (16,1500)
    const float* __restrict__ lcw,   // (500,8)
    const float* __restrict__ Wt,    // (500,16)
    const float* __restrict__ h3,    // (500,16,8)  == out3
    float* __restrict__ out1,        // (500,1500)
    float* __restrict__ out2)        // (500,16,8,1500)
{
    const int t = blockIdx.y;
    const int n = blockIdx.x * 256 + threadIdx.x;
    __shared__ float hc[SC];
    __shared__ float Ws[S];
    if (threadIdx.x < SC) {
        const int cc = threadIdx.x & 7;
        hc[threadIdx.x] = h3[t * SC + threadIdx.x] + lcw[t * C + cc];
    }
    if (threadIdx.x < S) Ws[threadIdx.x] = Wt[t * S + threadIdx.x];
    __syncthreads();
    if (n >= NN) return;

    float es[S];
#pragma unroll
    for (int s0 = 0; s0 < S; ++s0) es[s0] = lem[s0 * NN + n];

    float* o2 = out2 + (size_t)t * SC * NN + n;
#pragma unroll
    for (int s0 = 0; s0 < S; ++s0) {
#pragma unroll
        for (int cc = 0; cc < C; ++cc) {
            o2[(size_t)(s0 * C + cc) * NN] = es[s0] + hc[s0 * C + cc];
        }
    }

    float xs[S]; float m = -1e30f;
#pragma unroll
    for (int s0 = 0; s0 < S; ++s0) { xs[s0] = es[s0] + Ws[s0]; m = fmaxf(m, xs[s0]); }
    float acc = 0.f;
#pragma unroll
    for (int s0 = 0; s0 < S; ++s0) acc += fexp2((xs[s0] - m) * L2E);
    out1[(size_t)t * NN + n] = m + flog2(acc) * LN2;
}

extern "C" void kernel_launch(void* const* d_in, const int* in_sizes, int n_in,
                              void* d_out, int out_size, void* d_ws, size_t ws_size,
                              hipStream_t stream)
{
    const float* usi = (const float*)d_in[0];   // (16,8)
    const float* ucw = (const float*)d_in[1];   // (500,8)
    const float* uem = (const float*)d_in[2];   // (16,1,1500)
    const float* utm = (const float*)d_in[3];   // (8,16,16)

    float* out  = (float*)d_out;
    float* out1 = out;                                   // 750000
    float* out2 = out + 750000;                          // 96000000
    float* out3 = out + 750000 + 96000000;               // 64000

    float* ws      = (float*)d_ws;
    float* ws_lcw  = ws;            // 4000
    float* ws_W    = ws + 4000;     // 8000
    float* ws_lem  = ws + 12000;    // 24000

    emission_kernel<<<16, 256, 0, stream>>>(uem, ws_lem);
    hmm_serial<<<1, 64, 0, stream>>>(usi, ucw, utm, out3, ws_lcw, ws_W);
    broadcast_kernel<<<dim3(6, 500), 256, 0, stream>>>(ws_lem, ws_lcw, ws_W, out3, out1, out2);
}

// Round 2
// 194.729 us; speedup vs baseline: 3.3058x; 3.3058x over previous
//
#include <hip/hip_runtime.h>
#include <hip/hip_bf16.h>

#define S 16
#define C 8
#define SC 128
#define TT 500
#define NN 1500

__device__ __forceinline__ float fexp2(float x) { return exp2f(x); }
__device__ __forceinline__ float flog2(float x) { return log2f(x); }

#define L2E 1.4426950408889634f
#define LN2 0.6931471805599453f

// ---------------- Kernel A: emission log-softmax over N per state ----------
__global__ __launch_bounds__(256) void emission_kernel(
    const float* __restrict__ uem, float* __restrict__ lem)
{
    const int s0 = blockIdx.x;
    const float* row = uem + s0 * NN;
    const int tid = threadIdx.x;
    __shared__ float sm[4];
    __shared__ float ss[4];

    float m = -1e30f;
    for (int n = tid; n < NN; n += 256) m = fmaxf(m, row[n]);
#pragma unroll
    for (int off = 32; off >= 1; off >>= 1) m = fmaxf(m, __shfl_xor(m, off));
    if ((tid & 63) == 0) sm[tid >> 6] = m;
    __syncthreads();
    const float M = fmaxf(fmaxf(sm[0], sm[1]), fmaxf(sm[2], sm[3]));

    float acc = 0.f;
    for (int n = tid; n < NN; n += 256) acc += fexp2((row[n] - M) * L2E);
#pragma unroll
    for (int off = 32; off >= 1; off >>= 1) acc += __shfl_xor(acc, off);
    if ((tid & 63) == 0) ss[tid >> 6] = acc;
    __syncthreads();
    const float lse = M + flog2(ss[0] + ss[1] + ss[2] + ss[3]) * LN2;

    for (int n = tid; n < NN; n += 256) lem[s0 * NN + n] = row[n] - lse;
}

// ---------------- Kernel B: prob-domain HMM scan, 1 wave, registers only ---
// lane = c*8 + j ; lane holds p[j,c] (pa) and p[j+8,c] (pb).
__global__ __launch_bounds__(64) void hmm_scan(
    const float* __restrict__ usi,   // (16,8)
    const float* __restrict__ ucw,   // (500,8)
    const float* __restrict__ utm,   // (8,16,16)
    float* __restrict__ out3,        // (500,16,8) natural-log probs
    float* __restrict__ ws_lcw)      // (500,8)   natural-log chain weights
{
    __shared__ float pT[SC * S];     // prob-domain transition rows, row (c,s)
    const int lane = threadIdx.x;

    // log_softmax chain weights over C per row t (for broadcast kernel)
    for (int t = lane; t < TT; t += 64) {
        float x[C]; float m = -1e30f;
#pragma unroll
        for (int cc = 0; cc < C; ++cc) { x[cc] = ucw[t * C + cc]; m = fmaxf(m, x[cc]); }
        float acc = 0.f;
#pragma unroll
        for (int cc = 0; cc < C; ++cc) acc += fexp2((x[cc] - m) * L2E);
        const float lse = m + flog2(acc) * LN2;
#pragma unroll
        for (int cc = 0; cc < C; ++cc) ws_lcw[t * C + cc] = x[cc] - lse;
    }

    // softmax transition rows (over s'), PROB domain
    for (int r = lane; r < SC; r += 64) {
        float x[S]; float m = -1e30f;
#pragma unroll
        for (int k = 0; k < S; ++k) { x[k] = utm[r * S + k]; m = fmaxf(m, x[k]); }
        float acc = 0.f; float e[S];
#pragma unroll
        for (int k = 0; k < S; ++k) { e[k] = fexp2((x[k] - m) * L2E); acc += e[k]; }
        const float inv = 1.f / acc;
#pragma unroll
        for (int k = 0; k < S; ++k) pT[r * S + k] = e[k] * inv;
    }
    __syncthreads();

    const int c = lane >> 3;
    const int j = lane & 7;

    // per-lane transition columns (prob domain)
    float Ta[S], Tb[S];
#pragma unroll
    for (int s0 = 0; s0 < S; ++s0) {
        Ta[s0] = pT[(c * S + s0) * S + j];
        Tb[s0] = pT[(c * S + s0) * S + j + 8];
    }

    // p0 = softmax over states of usi[:,c]  (redundant across the 8 lanes of c)
    float x0[S]; float m0 = -1e30f;
#pragma unroll
    for (int s0 = 0; s0 < S; ++s0) { x0[s0] = usi[s0 * C + c]; m0 = fmaxf(m0, x0[s0]); }
    float acc0 = 0.f; float e0[S];
#pragma unroll
    for (int s0 = 0; s0 < S; ++s0) { e0[s0] = fexp2((x0[s0] - m0) * L2E); acc0 += e0[s0]; }
    const float lse0 = m0 + flog2(acc0) * LN2;
    const float inv0 = 1.f / acc0;
    float pa = e0[j] * inv0;
    float pb = e0[j + 8] * inv0;
    out3[j * C + c]       = x0[j] - lse0;
    out3[(j + 8) * C + c] = x0[j + 8] - lse0;

    const int base = c << 3;
    for (int t = 1; t < TT; ++t) {
        // allgather p[0..15, c] within the 8-lane chain group
        float pv[S];
#pragma unroll
        for (int i = 0; i < 8; ++i) {
            pv[i]     = __shfl(pa, base + i);
            pv[i + 8] = __shfl(pb, base + i);
        }
        // p'[s'] = sum_s p[s] * T[s,s']  — 4-way partial trees
        float a0 = 0.f, a1 = 0.f, a2 = 0.f, a3 = 0.f;
        float b0 = 0.f, b1 = 0.f, b2 = 0.f, b3 = 0.f;
#pragma unroll
        for (int s0 = 0; s0 < S; s0 += 4) {
            a0 = fmaf(pv[s0],     Ta[s0],     a0);
            a1 = fmaf(pv[s0 + 1], Ta[s0 + 1], a1);
            a2 = fmaf(pv[s0 + 2], Ta[s0 + 2], a2);
            a3 = fmaf(pv[s0 + 3], Ta[s0 + 3], a3);
            b0 = fmaf(pv[s0],     Tb[s0],     b0);
            b1 = fmaf(pv[s0 + 1], Tb[s0 + 1], b1);
            b2 = fmaf(pv[s0 + 2], Tb[s0 + 2], b2);
            b3 = fmaf(pv[s0 + 3], Tb[s0 + 3], b3);
        }
        pa = (a0 + a1) + (a2 + a3);
        pb = (b0 + b1) + (b2 + b3);

        float* o = out3 + t * SC;
        o[j * C + c]       = flog2(pa) * LN2;
        o[(j + 8) * C + c] = flog2(pb) * LN2;
    }
}

// ---------------- Kernel C: broadcast-add (out2) + LSE over s (out1) -------
// grid (3, 500), 256 threads; thread handles 2 consecutive n (float2)
__global__ __launch_bounds__(256) void broadcast_kernel(
    const float* __restrict__ lem,   // (16,1500)
    const float* __restrict__ lcw,   // (500,8)
    const float* __restrict__ h3,    // (500,16,8)  == out3
    float* __restrict__ out1,        // (500,1500)
    float* __restrict__ out2)        // (500,16,8,1500)
{
    const int t = blockIdx.y;
    const int tid = threadIdx.x;
    __shared__ float hc[SC];
    __shared__ float Ws[S];
    if (tid < SC) hc[tid] = h3[t * SC + tid] + lcw[t * C + (tid & 7)];
    __syncthreads();
    if (tid < S) {
        float m = -1e30f;
#pragma unroll
        for (int cc = 0; cc < C; ++cc) m = fmaxf(m, hc[tid * C + cc]);
        float acc = 0.f;
#pragma unroll
        for (int cc = 0; cc < C; ++cc) acc += fexp2((hc[tid * C + cc] - m) * L2E);
        Ws[tid] = m + flog2(acc) * LN2;
    }
    __syncthreads();

    const int n2 = blockIdx.x * 256 + tid;     // float2 index, 750 per row
    if (n2 >= 750) return;

    float2 es[S];
#pragma unroll
    for (int s0 = 0; s0 < S; ++s0)
        es[s0] = ((const float2*)(lem + s0 * NN))[n2];

    float* o2 = out2 + (size_t)t * SC * NN + 2 * n2;
#pragma unroll
    for (int s0 = 0; s0 < S; ++s0) {
#pragma unroll
        for (int cc = 0; cc < C; ++cc) {
            const float hv = hc[s0 * C + cc];
            *(float2*)(o2 + (size_t)(s0 * C + cc) * NN) =
                make_float2(es[s0].x + hv, es[s0].y + hv);
        }
    }

    float mx = -1e30f, my = -1e30f;
    float xs[S], ys[S];
#pragma unroll
    for (int s0 = 0; s0 < S; ++s0) {
        xs[s0] = es[s0].x + Ws[s0]; mx = fmaxf(mx, xs[s0]);
        ys[s0] = es[s0].y + Ws[s0]; my = fmaxf(my, ys[s0]);
    }
    float ax = 0.f, ay = 0.f;
#pragma unroll
    for (int s0 = 0; s0 < S; ++s0) {
        ax += fexp2((xs[s0] - mx) * L2E);
        ay += fexp2((ys[s0] - my) * L2E);
    }
    *(float2*)(out1 + (size_t)t * NN + 2 * n2) =
        make_float2(mx + flog2(ax) * LN2, my + flog2(ay) * LN2);
}

extern "C" void kernel_launch(void* const* d_in, const int* in_sizes, int n_in,
                              void* d_out, int out_size, void* d_ws, size_t ws_size,
                              hipStream_t stream)
{
    const float* usi = (const float*)d_in[0];   // (16,8)
    const float* ucw = (const float*)d_in[1];   // (500,8)
    const float* uem = (const float*)d_in[2];   // (16,1,1500)
    const float* utm = (const float*)d_in[3];   // (8,16,16)

    float* out  = (float*)d_out;
    float* out1 = out;                                   // 750000
    float* out2 = out + 750000;                          // 96000000
    float* out3 = out + 750000 + 96000000;               // 64000

    float* ws      = (float*)d_ws;
    float* ws_lcw  = ws;            // 4000
    float* ws_lem  = ws + 4000;     // 24000

    emission_kernel<<<16, 256, 0, stream>>>(uem, ws_lem);
    hmm_scan<<<1, 64, 0, stream>>>(usi, ucw, utm, out3, ws_lcw);
    broadcast_kernel<<<dim3(3, 500), 256, 0, stream>>>(ws_lem, ws_lcw, out3, out1, out2);
}

// Round 3
// 126.644 us; speedup vs baseline: 5.0831x; 1.5376x over previous
//
#include <hip/hip_runtime.h>
#include <hip/hip_bf16.h>

#define S 16
#define C 8
#define SC 128
#define TT 500
#define NN 1500
#define CHUNK 25
#define NCHUNK 20

__device__ __forceinline__ float fexp2(float x) { return exp2f(x); }
__device__ __forceinline__ float flog2(float x) { return log2f(x); }

#define L2E 1.4426950408889634f
#define LN2 0.6931471805599453f

// ---------------- Kernel A: emission log-softmax over N per state ----------
__global__ __launch_bounds__(256) void emission_kernel(
    const float* __restrict__ uem, float* __restrict__ lem)
{
    const int s0 = blockIdx.x;
    const float* row = uem + s0 * NN;
    const int tid = threadIdx.x;
    __shared__ float sm[4];
    __shared__ float ss[4];

    float m = -1e30f;
    for (int n = tid; n < NN; n += 256) m = fmaxf(m, row[n]);
#pragma unroll
    for (int off = 32; off >= 1; off >>= 1) m = fmaxf(m, __shfl_xor(m, off));
    if ((tid & 63) == 0) sm[tid >> 6] = m;
    __syncthreads();
    const float M = fmaxf(fmaxf(sm[0], sm[1]), fmaxf(sm[2], sm[3]));

    float acc = 0.f;
    for (int n = tid; n < NN; n += 256) acc += fexp2((row[n] - M) * L2E);
#pragma unroll
    for (int off = 32; off >= 1; off >>= 1) acc += __shfl_xor(acc, off);
    if ((tid & 63) == 0) ss[tid >> 6] = acc;
    __syncthreads();
    const float lse = M + flog2(ss[0] + ss[1] + ss[2] + ss[3]) * LN2;

    for (int n = tid; n < NN; n += 256) lem[s0 * NN + n] = row[n] - lse;
}

// ---------------- Kernel B1: normalizations + A=T^25 + chunk starts --------
// 1 block, 256 threads.
#define MM(dst, Asrc, Bsrc) do {                                          \
    __syncthreads();                                                      \
    {   const int c_ = tid >> 5; const int e0_ = tid & 31;                \
        for (int r_ = 0; r_ < 8; ++r_) {                                  \
            const int e_ = e0_ + (r_ << 5);                               \
            const int i_ = e_ >> 4; const int l_ = e_ & 15;               \
            float acc_ = 0.f;                                             \
            _Pragma("unroll")                                             \
            for (int s_ = 0; s_ < S; ++s_)                                \
                acc_ += Asrc[(c_ * S + i_) * S + s_] *                    \
                        Bsrc[(c_ * S + s_) * S + l_];                     \
            dst[(c_ * S + i_) * S + l_] = acc_;                          \
        } }                                                               \
} while (0)

__global__ __launch_bounds__(256) void hmm_setup(
    const float* __restrict__ usi,   // (16,8)
    const float* __restrict__ ucw,   // (500,8)
    const float* __restrict__ utm,   // (8,16,16)
    float* __restrict__ ws_lcw,      // (500,8)
    float* __restrict__ ws_pT,       // (8,16,16) prob-domain T
    float* __restrict__ ws_q)        // (20,8,16) chunk-start probs
{
    __shared__ float bufT[C * S * S];
    __shared__ float bufX[C * S * S];
    __shared__ float bufY[C * S * S];
    __shared__ float bufZ[C * S * S];
    __shared__ float qbuf[C * S];
    const int tid = threadIdx.x;

    // log_softmax chain weights over C per row t
    for (int t = tid; t < TT; t += 256) {
        float x[C]; float m = -1e30f;
#pragma unroll
        for (int cc = 0; cc < C; ++cc) { x[cc] = ucw[t * C + cc]; m = fmaxf(m, x[cc]); }
        float acc = 0.f;
#pragma unroll
        for (int cc = 0; cc < C; ++cc) acc += fexp2((x[cc] - m) * L2E);
        const float lse = m + flog2(acc) * LN2;
#pragma unroll
        for (int cc = 0; cc < C; ++cc) ws_lcw[t * C + cc] = x[cc] - lse;
    }

    // softmax transition rows (over s'), PROB domain
    if (tid < SC) {
        float x[S]; float m = -1e30f;
#pragma unroll
        for (int k = 0; k < S; ++k) { x[k] = utm[tid * S + k]; m = fmaxf(m, x[k]); }
        float acc = 0.f; float e[S];
#pragma unroll
        for (int k = 0; k < S; ++k) { e[k] = fexp2((x[k] - m) * L2E); acc += e[k]; }
        const float inv = 1.f / acc;
#pragma unroll
        for (int k = 0; k < S; ++k) {
            const float v = e[k] * inv;
            bufT[tid * S + k] = v;
            ws_pT[tid * S + k] = v;
        }
    }

    // p0 = softmax over states per chain
    if (tid < C) {
        const int cc = tid;
        float x[S]; float m = -1e30f;
#pragma unroll
        for (int s0 = 0; s0 < S; ++s0) { x[s0] = usi[s0 * C + cc]; m = fmaxf(m, x[s0]); }
        float acc = 0.f; float e[S];
#pragma unroll
        for (int s0 = 0; s0 < S; ++s0) { e[s0] = fexp2((x[s0] - m) * L2E); acc += e[s0]; }
        const float inv = 1.f / acc;
#pragma unroll
        for (int s0 = 0; s0 < S; ++s0) {
            const float v = e[s0] * inv;
            qbuf[cc * S + s0] = v;
            ws_q[cc * S + s0] = v;
        }
    }

    // A = T^25 per chain: T2, T4, T8, T16, T24, T25
    MM(bufX, bufT, bufT);   // T^2
    MM(bufY, bufX, bufX);   // T^4
    MM(bufZ, bufY, bufY);   // T^8
    MM(bufX, bufZ, bufZ);   // T^16
    MM(bufY, bufX, bufZ);   // T^24
    MM(bufX, bufY, bufT);   // T^25 -> bufX
    __syncthreads();

    // chunk starts: q_k = q_{k-1} * A, k = 1..19
    const int c5 = tid >> 4;
    const int l5 = tid & 15;
    float Acol[S];
    if (tid < 128) {
#pragma unroll
        for (int s0 = 0; s0 < S; ++s0) Acol[s0] = bufX[(c5 * S + s0) * S + l5];
    }
    for (int k = 1; k < NCHUNK; ++k) {
        float acc = 0.f;
        if (tid < 128) {
#pragma unroll
            for (int s0 = 0; s0 < S; ++s0) acc += qbuf[c5 * S + s0] * Acol[s0];
        }
        __syncthreads();
        if (tid < 128) {
            qbuf[c5 * S + l5] = acc;
            ws_q[k * SC + c5 * S + l5] = acc;
        }
        __syncthreads();
    }
}

// ---------------- Kernel B2: 20 parallel chunks of 25 serial steps ---------
// 64 threads/block; lane = c*8 + j holds p[j,c], p[j+8,c].
__global__ __launch_bounds__(64) void hmm_chunks(
    const float* __restrict__ ws_pT, // (8,16,16) prob T
    const float* __restrict__ ws_q,  // (20,8,16)
    float* __restrict__ out3)        // (500,16,8) natural-log probs
{
    const int k = blockIdx.x;
    const int lane = threadIdx.x;
    const int c = lane >> 3;
    const int j = lane & 7;

    float Ta[S], Tb[S];
#pragma unroll
    for (int s0 = 0; s0 < S; ++s0) {
        Ta[s0] = ws_pT[(c * S + s0) * S + j];
        Tb[s0] = ws_pT[(c * S + s0) * S + j + 8];
    }
    float pa = ws_q[k * SC + c * S + j];
    float pb = ws_q[k * SC + c * S + j + 8];

    const int base = c << 3;
    for (int i = 0; i < CHUNK; ++i) {
        float* o = out3 + (size_t)(k * CHUNK + i) * SC;
        o[j * C + c]       = flog2(pa) * LN2;
        o[(j + 8) * C + c] = flog2(pb) * LN2;
        if (i == CHUNK - 1) break;

        float pv[S];
#pragma unroll
        for (int q = 0; q < 8; ++q) {
            pv[q]     = __shfl(pa, base + q);
            pv[q + 8] = __shfl(pb, base + q);
        }
        float a0 = 0.f, a1 = 0.f, a2 = 0.f, a3 = 0.f;
        float b0 = 0.f, b1 = 0.f, b2 = 0.f, b3 = 0.f;
#pragma unroll
        for (int s0 = 0; s0 < S; s0 += 4) {
            a0 = fmaf(pv[s0],     Ta[s0],     a0);
            a1 = fmaf(pv[s0 + 1], Ta[s0 + 1], a1);
            a2 = fmaf(pv[s0 + 2], Ta[s0 + 2], a2);
            a3 = fmaf(pv[s0 + 3], Ta[s0 + 3], a3);
            b0 = fmaf(pv[s0],     Tb[s0],     b0);
            b1 = fmaf(pv[s0 + 1], Tb[s0 + 1], b1);
            b2 = fmaf(pv[s0 + 2], Tb[s0 + 2], b2);
            b3 = fmaf(pv[s0 + 3], Tb[s0 + 3], b3);
        }
        pa = (a0 + a1) + (a2 + a3);
        pb = (b0 + b1) + (b2 + b3);
    }
}

// ---------------- Kernel C: broadcast-add (out2) + LSE over s (out1) -------
// grid (3, 500), 128 threads; thread handles 4 consecutive n (float4)
__global__ __launch_bounds__(128) void broadcast_kernel(
    const float* __restrict__ lem,   // (16,1500)
    const float* __restrict__ lcw,   // (500,8)
    const float* __restrict__ h3,    // (500,16,8)  == out3
    float* __restrict__ out1,        // (500,1500)
    float* __restrict__ out2)        // (500,16,8,1500)
{
    const int t = blockIdx.y;
    const int tid = threadIdx.x;
    __shared__ float hc[SC];
    __shared__ float Ws[S];
    if (tid < SC) hc[tid] = h3[t * SC + tid] + lcw[t * C + (tid & 7)];
    __syncthreads();
    if (tid < S) {
        float m = -1e30f;
#pragma unroll
        for (int cc = 0; cc < C; ++cc) m = fmaxf(m, hc[tid * C + cc]);
        float acc = 0.f;
#pragma unroll
        for (int cc = 0; cc < C; ++cc) acc += fexp2((hc[tid * C + cc] - m) * L2E);
        Ws[tid] = m + flog2(acc) * LN2;
    }
    __syncthreads();

    const int n4 = blockIdx.x * 128 + tid;     // float4 index, 375 per row
    if (n4 >= 375) return;

    float4 es[S];
#pragma unroll
    for (int s0 = 0; s0 < S; ++s0)
        es[s0] = ((const float4*)(lem + s0 * NN))[n4];

    float* o2 = out2 + (size_t)t * SC * NN + 4 * n4;
#pragma unroll
    for (int s0 = 0; s0 < S; ++s0) {
#pragma unroll
        for (int cc = 0; cc < C; ++cc) {
            const float hv = hc[s0 * C + cc];
            float4 v = es[s0];
            v.x += hv; v.y += hv; v.z += hv; v.w += hv;
            *(float4*)(o2 + (size_t)(s0 * C + cc) * NN) = v;
        }
    }

    float4 mv = make_float4(-1e30f, -1e30f, -1e30f, -1e30f);
    float4 xs[S];
#pragma unroll
    for (int s0 = 0; s0 < S; ++s0) {
        const float w = Ws[s0];
        xs[s0].x = es[s0].x + w; mv.x = fmaxf(mv.x, xs[s0].x);
        xs[s0].y = es[s0].y + w; mv.y = fmaxf(mv.y, xs[s0].y);
        xs[s0].z = es[s0].z + w; mv.z = fmaxf(mv.z, xs[s0].z);
        xs[s0].w = es[s0].w + w; mv.w = fmaxf(mv.w, xs[s0].w);
    }
    float4 av = make_float4(0.f, 0.f, 0.f, 0.f);
#pragma unroll
    for (int s0 = 0; s0 < S; ++s0) {
        av.x += fexp2((xs[s0].x - mv.x) * L2E);
        av.y += fexp2((xs[s0].y - mv.y) * L2E);
        av.z += fexp2((xs[s0].z - mv.z) * L2E);
        av.w += fexp2((xs[s0].w - mv.w) * L2E);
    }
    float4 r;
    r.x = mv.x + flog2(av.x) * LN2;
    r.y = mv.y + flog2(av.y) * LN2;
    r.z = mv.z + flog2(av.z) * LN2;
    r.w = mv.w + flog2(av.w) * LN2;
    *(float4*)(out1 + (size_t)t * NN + 4 * n4) = r;
}

extern "C" void kernel_launch(void* const* d_in, const int* in_sizes, int n_in,
                              void* d_out, int out_size, void* d_ws, size_t ws_size,
                              hipStream_t stream)
{
    const float* usi = (const float*)d_in[0];   // (16,8)
    const float* ucw = (const float*)d_in[1];   // (500,8)
    const float* uem = (const float*)d_in[2];   // (16,1,1500)
    const float* utm = (const float*)d_in[3];   // (8,16,16)

    float* out  = (float*)d_out;
    float* out1 = out;                                   // 750000
    float* out2 = out + 750000;                          // 96000000
    float* out3 = out + 750000 + 96000000;               // 64000

    float* ws      = (float*)d_ws;
    float* ws_lcw  = ws;             // 4000
    float* ws_lem  = ws + 4000;      // 24000
    float* ws_pT   = ws + 28000;     // 2048
    float* ws_q    = ws + 30048;     // 2560

    emission_kernel<<<16, 256, 0, stream>>>(uem, ws_lem);
    hmm_setup<<<1, 256, 0, stream>>>(usi, ucw, utm, ws_lcw, ws_pT, ws_q);
    hmm_chunks<<<NCHUNK, 64, 0, stream>>>(ws_pT, ws_q, out3);
    broadcast_kernel<<<dim3(3, 500), 128, 0, stream>>>(ws_lem, ws_lcw, out3, out1, out2);
}